// Round 5
// baseline (90236.975 us; speedup 1.0000x reference)
//
#include <hip/hip_runtime.h>
#include <hip/hip_fp16.h>
#include <math.h>
#include <stdint.h>

// MobiusGRU T=256 B=64 D=H=512, 2 layers.
// R5 vs R4: k_scan parallelized 4 WGs per batch row (256 WGs, all 256 CUs).
// Each WG owns a 128-col slice of z/r/cand; per-CU weight stream 1.5MB->384KB/step.
// Cross-WG: 5 device-scope exchange rounds/step (S1 dots, S2 wv+W2, S3 dots,
// S4 dots, S5 h-gather) via monotone counters + atomic slots. Weight loads
// prefetched into VGPRs before the h-poll to overlap stream with sync latency.

#define T_  256
#define B_  64
#define H_  512
#define G3_ 1536
#define EPSF 1e-15f
#define CLIPF (1.0f - 1e-5f)
#define SCOPE_AGENT __HIP_MEMORY_SCOPE_AGENT

typedef _Float16 v2h __attribute__((ext_vector_type(2)));

__device__ __forceinline__ float fdot2_(unsigned int w, unsigned int h, float c){
#if __has_builtin(__builtin_amdgcn_fdot2)
  return __builtin_amdgcn_fdot2(__builtin_bit_cast(v2h, w), __builtin_bit_cast(v2h, h), c, false);
#else
  const __half2 wh = __builtin_bit_cast(__half2, w);
  const __half2 hh = __builtin_bit_cast(__half2, h);
  return c + __low2float(wh)*__low2float(hh) + __high2float(wh)*__high2float(hh);
#endif
}

__device__ __forceinline__ float artanh_c(float x){
  x = fminf(fmaxf(x, -CLIPF), CLIPF);
  return 0.5f * logf((1.0f + x) / (1.0f - x));
}
__device__ __forceinline__ float sigmoidf_(float x){ return 1.0f/(1.0f+expf(-x)); }
__device__ __forceinline__ float hsum4(float4 v){ return (v.x+v.y)+(v.z+v.w); }

// reduce NS values across the wave; lane0 stores red[s*8 + wave] (8 waves)
template<int NS>
__device__ __forceinline__ void wave_reduce_store(float (&v)[NS], float* red, int tid){
  #pragma unroll
  for (int off = 32; off > 0; off >>= 1)
    #pragma unroll
    for (int s = 0; s < NS; s++) v[s] += __shfl_xor(v[s], off);
  if ((tid & 63) == 0)
    #pragma unroll
    for (int s = 0; s < NS; s++) red[s*8 + (tid >> 6)] = v[s];
}

__device__ __forceinline__ void arrive_(int* c){
  __threadfence();
  __syncthreads();
  if (threadIdx.x == 0)
    __hip_atomic_fetch_add(c, 1, __ATOMIC_RELEASE, SCOPE_AGENT);
}
__device__ __forceinline__ void wait_(int* c, int tgt){
  if (threadIdx.x == 0){
    while (__hip_atomic_load(c, __ATOMIC_ACQUIRE, SCOPE_AGENT) < tgt)
      __builtin_amdgcn_s_sleep(1);
  }
  __syncthreads();
}

// ---- transpose weight_ih [1536][512] -> WihT [512][1536]
__global__ void k_prep_ih(const float* __restrict__ Wih, float* __restrict__ WihT){
  int i = blockIdx.x * blockDim.x + threadIdx.x;
  if (i >= H_ * G3_) return;
  int k = i / G3_, n = i % G3_;
  WihT[i] = Wih[n * H_ + k];
}

__device__ __forceinline__ uint2 packh4(const float* s){
  __half2 lo = __halves2half2(__float2half_rn(s[0]), __float2half_rn(s[1]));
  __half2 hi = __halves2half2(__float2half_rn(s[2]), __float2half_rn(s[3]));
  uint2 r;
  r.x = __builtin_bit_cast(unsigned int, lo);
  r.y = __builtin_bit_cast(unsigned int, hi);
  return r;
}

// ---- weight_hh -> per-WG packed slices (f16, 4-k-wide)
// WzrP[w][k4][256]: cols 0..127 = z_{128w+c} (Whh row 1024+j), 128..255 = r (Whh row j)
// WhcP[w][k4][128]: cand j = 128w+c (Whh row 512+j)
__global__ void k_prep_hhP(const float* __restrict__ Whh, uint2* __restrict__ WzrP,
                           uint2* __restrict__ WhcP){
  int i = blockIdx.x * blockDim.x + threadIdx.x;   // 196608 total
  if (i < 131072){
    int w = i >> 15, rem = i & 32767;
    int k4 = rem >> 8, c = rem & 255;
    int j = w*128 + (c & 127);
    int row = (c < 128) ? (1024 + j) : j;
    WzrP[i] = packh4(Whh + row*H_ + 4*k4);
  } else {
    int i2 = i - 131072;
    int w = i2 >> 14, rem = i2 & 16383;
    int k4 = rem >> 7, c = rem & 127;
    int row = 512 + w*128 + c;
    WhcP[i2] = packh4(Whh + row*H_ + 4*k4);
  }
}

// ---- tiled f32 GEMM: C[16384][1536] = A[16384][512] * Bt[512][1536]
__global__ __launch_bounds__(256) void k_gemm(const float* __restrict__ A,
                                              const float* __restrict__ Bt,
                                              float* __restrict__ C){
  const int N = G3_, K = H_;
  const int mbase = blockIdx.x * 64, nbase = blockIdx.y * 64;
  __shared__ float As[32][65];
  __shared__ float Bs[32][65];
  const int tid = threadIdx.x;
  const int tm = tid >> 4, tn = tid & 15;
  float acc[4][4] = {};
  for (int k0 = 0; k0 < K; k0 += 32){
    #pragma unroll
    for (int i = 0; i < 8; i++){
      int e = tid + 256*i;
      int m = e >> 5, k = e & 31;
      As[k][m] = A[(size_t)(mbase + m) * K + k0 + k];
      int kk = e >> 6, n = e & 63;
      Bs[kk][n] = Bt[(size_t)(k0 + kk) * N + nbase + n];
    }
    __syncthreads();
    #pragma unroll
    for (int kk = 0; kk < 32; kk++){
      float av[4], bv[4];
      #pragma unroll
      for (int i = 0; i < 4; i++) av[i] = As[kk][tm*4+i];
      #pragma unroll
      for (int j = 0; j < 4; j++) bv[j] = Bs[kk][tn*4+j];
      #pragma unroll
      for (int i = 0; i < 4; i++)
        #pragma unroll
        for (int j = 0; j < 4; j++)
          acc[i][j] = fmaf(av[i], bv[j], acc[i][j]);
    }
    __syncthreads();
  }
  #pragma unroll
  for (int i = 0; i < 4; i++)
    #pragma unroll
    for (int j = 0; j < 4; j++)
      C[(size_t)(mbase + tm*4 + i) * N + nbase + tn*4 + j] = acc[i][j];
}

// ---- mobius_matvec tail on Ux rows
__global__ void k_nonlin(const float* __restrict__ X, float* __restrict__ D){
  const int row = blockIdx.x;
  const int lane = threadIdx.x;
  const float* x = X + (size_t)row * H_;
  float s = 0.0f;
  for (int k = lane; k < H_; k += 64){ float v = x[k]; s = fmaf(v, v, s); }
  #pragma unroll
  for (int off = 32; off > 0; off >>= 1) s += __shfl_xor(s, off);
  const float xn = fmaxf(sqrtf(s), EPSF);
  const float art = artanh_c(xn);
  float* drow = D + (size_t)row * G3_;
  for (int g = 0; g < 3; g++){
    float* mx = drow + g * H_;
    float s2 = 0.0f;
    for (int k = lane; k < H_; k += 64){ float v = mx[k]; s2 = fmaf(v, v, s2); }
    #pragma unroll
    for (int off = 32; off > 0; off >>= 1) s2 += __shfl_xor(s2, off);
    const float raw = sqrtf(s2);
    const float mn = fmaxf(raw, EPSF);
    const float scale = (raw <= EPSF) ? 0.0f : (tanhf(mn / xn * art) / mn);
    for (int k = lane; k < H_; k += 64) mx[k] *= scale;
  }
}

// ---- scan: 4 WGs per row (256 WGs x 512 thr). WG w of row b owns cols [128w,128w+128).
__global__ __launch_bounds__(512) void k_scan(
    const float* __restrict__ D,       // Ux' [T*B][1536]: r|c|z
    const uint2* __restrict__ WzrP,    // per-WG [128 k4][256 cols z|r]
    const uint2* __restrict__ WhcP,    // per-WG [128 k4][128 cols]
    const float* __restrict__ bias,    // [3][512] = b_r, b_c, b_z
    const float* __restrict__ h0,
    float* __restrict__ outbuf,        // [T][64][512]
    float* __restrict__ hlast,
    float* __restrict__ Sl,            // [64 rows][4 rounds][4 wg][16]
    int* __restrict__ cnt,             // [64 rows][16] (5 used)
    float* __restrict__ wvbuf,         // [64][512]
    float* __restrict__ hbuf)          // [64][512]
{
  const int blk = blockIdx.x;
  const int b = blk & 63, w = blk >> 6;   // group members share blk%8 -> same XCD
  const int tid = threadIdx.x;
  const int lane = tid & 63, wave = tid >> 6;
  __shared__ __align__(16) __half hh[H_];
  __shared__ __align__(16) float hf[H_];
  __shared__ __align__(16) __half wvh[H_];
  __shared__ __align__(16) float ph[512];
  __shared__ __align__(16) float red[96];
  __shared__ __align__(16) float xr[16];

  float* SlRow = Sl + b*256;
  int* cntRow  = cnt + b*16;
  float* wvRow = wvbuf + b*H_;
  float* hRow  = hbuf + b*H_;

  {
    const float hv0 = h0[b*H_ + tid];
    hf[tid] = hv0;
    hh[tid] = __float2half_rn(hv0);
  }
  // bias norms (full vectors -> local, identical in all WGs)
  float B2z, B2r, BC2;
  {
    const float vz = bias[1024 + tid], vr = bias[tid], vc = bias[512 + tid];
    float vb[3] = { vz*vz, vr*vr, vc*vc };
    wave_reduce_store<3>(vb, red, tid);
    __syncthreads();
    const float4* p = (const float4*)red;
    B2z = hsum4(p[0]) + hsum4(p[1]);
    B2r = hsum4(p[2]) + hsum4(p[3]);
    BC2 = hsum4(p[4]) + hsum4(p[5]);
    __syncthreads();
  }

  const int colA = tid & 255, ks = tid >> 8;     // phase A: col + k-slice(2)
  const int jloc = tid & 127;
  const int jglob = w*128 + jloc;
  const bool isZ = (tid < 128);
  const bool isGate = (tid < 256);
  const float bval = isGate ? (isZ ? bias[1024 + jglob] : bias[jglob]) : 0.f;
  const float bcj  = (tid < 128) ? bias[512 + jglob] : 0.f;
  const float B2own = isZ ? B2z : B2r;
  const int s4 = tid >> 7;                       // phase B k-slice(4)
  const uint2* baseA = WzrP + (size_t)w*32768 + colA;
  const uint2* baseB = WhcP + (size_t)w*16384 + jloc;
  const uint2* hh4 = (const uint2*)hh;
  const uint2* wv4 = (const uint2*)wvh;
  const float* Dbase = D + (size_t)b * G3_;

  float zreg = 0.f;
  for (int t = 0; t < T_; t++){
    const float* U = Dbase + (size_t)t * (B_ * G3_);
    // prefetch phase-A weight slice (drains during h-poll)
    uint2 wA[64];
    #pragma unroll
    for (int i = 0; i < 64; i++) wA[i] = baseA[(ks*64 + i)*256];
    // S5: h exchange from previous step
    if (t > 0){
      wait_(cntRow + 4, 4*t);
      const float hvv = __hip_atomic_load(hRow + tid, __ATOMIC_RELAXED, SCOPE_AGENT);
      hf[tid] = hvv;
      hh[tid] = __float2half_rn(hvv);
      __syncthreads();
    }
    const float hv = hf[tid];
    // phase A partial dot
    float ap = 0.f;
    #pragma unroll
    for (int i = 0; i < 64; i++){
      const uint2 hp = hh4[ks*64 + i];
      ap = fdot2_(wA[i].x, hp.x, ap);
      ap = fdot2_(wA[i].y, hp.y, ap);
    }
    ph[tid] = ap;
    // prefetch phase-B weight slice (drains across S1/S2)
    uint2 wB[32];
    #pragma unroll
    for (int i = 0; i < 32; i++) wB[i] = baseB[(s4*32 + i)*128];
    __syncthreads();
    const float a = isGate ? (ph[tid] + ph[tid + 256]) : 0.f;
    const float y = isGate ? (isZ ? U[1024 + jglob] : U[jglob]) : 0.f;
    // S1 local dots: {h2 | z: a2,ay,y2,ab,yb | r: a2,ay,y2,ab,yb}
    {
      float v[11];
      v[0] = hv*hv;
      #pragma unroll
      for (int s = 1; s < 11; s++) v[s] = 0.f;
      if (isGate){
        const int o = isZ ? 1 : 6;
        v[o] = a*a; v[o+1] = a*y; v[o+2] = y*y; v[o+3] = a*bval; v[o+4] = y*bval;
      }
      wave_reduce_store<11>(v, red, tid);
    }
    __syncthreads();
    float H2;
    { const float4* p = (const float4*)red; H2 = hsum4(p[0]) + hsum4(p[1]); }
    if (wave == 0 && lane < 10){
      float s = 0.f;
      const float* r = red + (1 + lane)*8;
      #pragma unroll
      for (int i = 0; i < 8; i++) s += r[i];
      __hip_atomic_store(SlRow + w*16 + lane, s, __ATOMIC_RELAXED, SCOPE_AGENT);
    }
    arrive_(cntRow + 0);
    wait_(cntRow + 0, 4*(t+1));
    if (wave == 0){
      const int wgi = lane >> 4, s = lane & 15;
      float v = (s < 10) ? __hip_atomic_load(SlRow + wgi*16 + s, __ATOMIC_RELAXED, SCOPE_AGENT) : 0.f;
      v += __shfl_xor(v, 16);
      v += __shfl_xor(v, 32);
      if (lane < 16) xr[lane] = v;
    }
    __syncthreads();
    // gate math (z: waves 0-1, r: waves 2-3)
    const float xn = fmaxf(sqrtf(H2), EPSF);
    const float art_h = artanh_c(xn);
    float wv_val = 0.f;
    if (isGate){
      const int o = isZ ? 0 : 5;
      const float A2 = xr[o], AY = xr[o+1], Yy2 = xr[o+2], AB = xr[o+3], YB = xr[o+4];
      const float mraw = sqrtf(A2);
      const float mnc = fmaxf(mraw, EPSF);
      const float alpha = (mraw <= EPSF) ? 0.f : (tanhf(mnc/xn*art_h)/mnc);
      const float X2 = alpha*alpha*A2, XY = alpha*AY, XB = alpha*AB;
      const float cA1 = 1.f + 2.f*XY + Yy2, cB1 = 1.f - X2;
      const float den1 = fmaxf(1.f + 2.f*XY + X2*Yy2, EPSF), id1 = 1.f/den1;
      const float T2 = fmaxf((cA1*cA1*X2 + 2.f*cA1*cB1*XY + cB1*cB1*Yy2)*id1*id1, 0.f);
      const float TB = (cA1*XB + cB1*YB)*id1;
      const float cA2 = 1.f + 2.f*TB + B2own, cB2 = 1.f - T2;
      const float den2 = fmaxf(1.f + 2.f*TB + T2*B2own, EPSF), id2 = 1.f/den2;
      const float U2 = fmaxf((cA2*cA2*T2 + 2.f*cA2*cB2*TB + cB2*cB2*B2own)*id2*id2, 0.f);
      const float un = fmaxf(sqrtf(U2), EPSF);
      const float lsc = artanh_c(un)/un;
      const float t1el = (cA1*(alpha*a) + cB1*y)*id1;
      const float uel  = (cA2*t1el + cB2*bval)*id2;
      const float g = sigmoidf_(lsc*uel);
      if (isZ) zreg = g;
      else {
        wv_val = g * hf[jglob];
        __hip_atomic_store(wvRow + jglob, wv_val, __ATOMIC_RELAXED, SCOPE_AGENT);
      }
    }
    // S2: W2 allreduce + wv gather
    {
      float v1[1] = { wv_val*wv_val };
      wave_reduce_store<1>(v1, red, tid);
    }
    __syncthreads();
    if (wave == 0 && lane == 0){
      float s = 0.f;
      #pragma unroll
      for (int i = 0; i < 8; i++) s += red[i];
      __hip_atomic_store(SlRow + 64 + w*16, s, __ATOMIC_RELAXED, SCOPE_AGENT);
    }
    arrive_(cntRow + 1);
    wait_(cntRow + 1, 4*(t+1));
    {
      const float wvv = __hip_atomic_load(wvRow + tid, __ATOMIC_RELAXED, SCOPE_AGENT);
      wvh[tid] = __float2half_rn(wvv);
    }
    if (wave == 0){
      float v = (lane < 4) ? __hip_atomic_load(SlRow + 64 + lane*16, __ATOMIC_RELAXED, SCOPE_AGENT) : 0.f;
      v += __shfl_xor(v, 1);
      v += __shfl_xor(v, 2);
      if (lane == 0) xr[0] = v;
    }
    __syncthreads();
    const float W2 = xr[0];
    const float wraw = sqrtf(W2);
    const float wn = fmaxf(wraw, EPSF);
    const float mu = (wraw <= EPSF) ? 0.f : (tanhf(wn/xn*art_h)/wn);
    const float rhn = fmaxf(mu*wraw, EPSF);
    // phase B partial dot (raw wv; mu applied at combine)
    float cp = 0.f;
    #pragma unroll
    for (int i = 0; i < 32; i++){
      const uint2 wp2 = wv4[s4*32 + i];
      cp = fdot2_(wB[i].x, wp2.x, cp);
      cp = fdot2_(wB[i].y, wp2.y, cp);
    }
    ph[tid] = cp;
    __syncthreads();
    float cel = 0.f, ycel = 0.f, hj = 0.f;
    if (tid < 128){
      cel  = mu * (ph[tid] + ph[tid+128] + ph[tid+256] + ph[tid+384]);
      ycel = U[512 + jglob];
      hj   = hf[jglob];
    }
    // S3: candidate dots {c2,cy,y2,cb,yb,hc,hy,hb}
    {
      float v[8] = { cel*cel, cel*ycel, ycel*ycel, cel*bcj,
                     ycel*bcj, hj*cel, hj*ycel, hj*bcj };
      wave_reduce_store<8>(v, red, tid);
    }
    __syncthreads();
    if (wave == 0 && lane < 8){
      float s = 0.f;
      const float* r = red + lane*8;
      #pragma unroll
      for (int i = 0; i < 8; i++) s += r[i];
      __hip_atomic_store(SlRow + 128 + w*16 + lane, s, __ATOMIC_RELAXED, SCOPE_AGENT);
    }
    arrive_(cntRow + 2);
    wait_(cntRow + 2, 4*(t+1));
    if (wave == 0){
      const int wgi = lane >> 4, s = lane & 15;
      float v = (s < 8) ? __hip_atomic_load(SlRow + 128 + wgi*16 + s, __ATOMIC_RELAXED, SCOPE_AGENT) : 0.f;
      v += __shfl_xor(v, 16);
      v += __shfl_xor(v, 32);
      if (lane < 16) xr[lane] = v;
    }
    __syncthreads();
    const float C2 = xr[0], CY = xr[1], Y2c = xr[2], CB = xr[3],
                YBc = xr[4], HC = xr[5], HYd = xr[6], HBd = xr[7];
    const float craw = sqrtf(C2);
    const float cmn2 = fmaxf(craw, EPSF);
    const float alc = (craw <= EPSF) ? 0.f : (tanhf(cmn2/rhn*artanh_c(rhn))/cmn2);
    const float X2c = alc*alc*C2, XYc = alc*CY, XBc = alc*CB, HXc = alc*HC;
    const float cA1c = 1.f + 2.f*XYc + Y2c, cB1c = 1.f - X2c;
    const float den1c = fmaxf(1.f + 2.f*XYc + X2c*Y2c, EPSF), id1c = 1.f/den1c;
    const float T2c = fmaxf((cA1c*cA1c*X2c + 2.f*cA1c*cB1c*XYc + cB1c*cB1c*Y2c)*id1c*id1c, 0.f);
    const float TBc = (cA1c*XBc + cB1c*YBc)*id1c;
    const float HT1 = (cA1c*HXc + cB1c*HYd)*id1c;
    const float cA2c = 1.f + 2.f*TBc + BC2, cB2c = 1.f - T2c;
    const float den2c = fmaxf(1.f + 2.f*TBc + T2c*BC2, EPSF), id2c = 1.f/den2c;
    const float HTL2 = fmaxf((cA2c*cA2c*T2c + 2.f*cA2c*cB2c*TBc + cB2c*cB2c*BC2)*id2c*id2c, 0.f);
    const float HHTL = (cA2c*HT1 + cB2c*HBd)*id2c;
    const float cAd = 1.f - 2.f*HHTL + HTL2, cBd = 1.f - H2;
    const float dend = fmaxf(1.f - 2.f*HHTL + H2*HTL2, EPSF), idd = 1.f/dend;
    float del = 0.f, w2el = 0.f;
    if (tid < 128){
      const float t1cel = (cA1c*(alc*cel) + cB1c*ycel)*id1c;
      const float htlel = (cA2c*t1cel + cB2c*bcj)*id2c;
      del = (cAd*(-hj) + cBd*htlel)*idd;
      w2el = zreg*del;
    }
    // S4: {d2, |z.*d|2, h.(z.*d)}
    {
      float v[3] = { del*del, w2el*w2el, hj*w2el };
      wave_reduce_store<3>(v, red, tid);
    }
    __syncthreads();
    if (wave == 0 && lane < 3){
      float s = 0.f;
      const float* r = red + lane*8;
      #pragma unroll
      for (int i = 0; i < 8; i++) s += r[i];
      __hip_atomic_store(SlRow + 192 + w*16 + lane, s, __ATOMIC_RELAXED, SCOPE_AGENT);
    }
    arrive_(cntRow + 3);
    wait_(cntRow + 3, 4*(t+1));
    if (wave == 0){
      const int wgi = lane >> 4, s = lane & 15;
      float v = (s < 3) ? __hip_atomic_load(SlRow + 192 + wgi*16 + s, __ATOMIC_RELAXED, SCOPE_AGENT) : 0.f;
      v += __shfl_xor(v, 16);
      v += __shfl_xor(v, 32);
      if (lane < 16) xr[lane] = v;
    }
    __syncthreads();
    const float D2v = xr[0], W22 = xr[1], HW = xr[2];
    const float dnv = fmaxf(sqrtf(D2v), EPSF);
    const float w2raw = sqrtf(W22);
    const float w2n = fmaxf(w2raw, EPSF);
    const float nu = (w2raw <= EPSF) ? 0.f : (tanhf(w2n/dnv*artanh_c(dnv))/w2n);
    const float Y2f = nu*nu*W22, XYf = nu*HW;
    const float cAf = 1.f + 2.f*XYf + Y2f, cBf = 1.f - H2;
    const float denf = fmaxf(1.f + 2.f*XYf + H2*Y2f, EPSF), idf = 1.f/denf;
    if (tid < 128){
      const float hnew = (cAf*hj + cBf*(nu*w2el))*idf;
      outbuf[(size_t)(t*B_ + b)*H_ + jglob] = hnew;
      __hip_atomic_store(hRow + jglob, hnew, __ATOMIC_RELAXED, SCOPE_AGENT);
      if (t == T_-1) hlast[b*H_ + jglob] = hnew;
    }
    arrive_(cntRow + 4);
  }
}

extern "C" void kernel_launch(void* const* d_in, const int* in_sizes, int n_in,
                              void* d_out, int out_size, void* d_ws, size_t ws_size,
                              hipStream_t stream){
  (void)in_sizes; (void)n_in; (void)out_size; (void)ws_size;
  const float* input = (const float*)d_in[0];
  const float* h0    = (const float*)d_in[1];
  const float* wih1  = (const float*)d_in[2];
  const float* wih2  = (const float*)d_in[3];
  const float* whh1  = (const float*)d_in[4];
  const float* whh2  = (const float*)d_in[5];
  const float* bias1 = (const float*)d_in[6];
  const float* bias2 = (const float*)d_in[7];
  float* out = (float*)d_out;

  // ws (floats): WihT 786432 | Dbuf 25165824 | WzrP 131072 u2 | WhcP 65536 u2
  //              Sl 16384 | wvbuf 32768 | hbuf 32768 | cnt 1024 ints  (~106 MB)
  float* A_    = (float*)d_ws;
  float* Dbuf  = A_ + 786432;
  uint2* WzrP  = (uint2*)(Dbuf + 25165824);
  uint2* WhcP  = WzrP + 131072;
  float* Sl    = (float*)(WhcP + 65536);
  float* wvbuf = Sl + 16384;
  float* hbuf  = wvbuf + 32768;
  int*   cnt   = (int*)(hbuf + 32768);

  float* out1 = out;                          // staged; consumed before scan-2 overwrites
  float* ht   = out + (size_t)T_ * B_ * H_;

  // layer 1
  k_prep_ih<<<3072, 256, 0, stream>>>(wih1, A_);
  k_gemm<<<dim3(256, 24), 256, 0, stream>>>(input, A_, Dbuf);
  k_nonlin<<<T_*B_, 64, 0, stream>>>(input, Dbuf);
  k_prep_hhP<<<768, 256, 0, stream>>>(whh1, WzrP, WhcP);
  hipMemsetAsync(cnt, 0, 64*16*sizeof(int), stream);
  k_scan<<<256, 512, 0, stream>>>(Dbuf, WzrP, WhcP, bias1, h0, out1, ht,
                                  Sl, cnt, wvbuf, hbuf);

  // layer 2
  k_prep_ih<<<3072, 256, 0, stream>>>(wih2, A_);
  k_gemm<<<dim3(256, 24), 256, 0, stream>>>(out1, A_, Dbuf);
  k_nonlin<<<T_*B_, 64, 0, stream>>>(out1, Dbuf);
  k_prep_hhP<<<768, 256, 0, stream>>>(whh2, WzrP, WhcP);
  hipMemsetAsync(cnt, 0, 64*16*sizeof(int), stream);
  k_scan<<<256, 512, 0, stream>>>(Dbuf, WzrP, WhcP, bias2, h0 + B_*H_, out, ht + B_*H_,
                                  Sl, cnt, wvbuf, hbuf);
}

// Round 7
// 7755.698 us; speedup vs baseline: 11.6349x; 11.6349x over previous
//
#include <hip/hip_runtime.h>
#include <hip/hip_fp16.h>
#include <math.h>
#include <stdint.h>

// MobiusGRU T=256 B=64 D=H=512, 2 layers.
// R7 = R6 with the h-exchange tag off-by-one fixed (post tag, not tag+1).
// Design: 4 WGs per batch row (256 WGs x 512 thr, ~1/CU). Weight slices live
// in VGPRs (48 uint4/thread) -> zero per-step weight streaming. Cross-WG
// exchange is fence-free: 64-bit {tag,value} relaxed agent atomics (no
// buffer_inv/wbl2). 5 exchange rounds/step; interlocking rounds make each
// slot's overwrite ordered behind all its readers (no ABA).

#define T_  256
#define B_  64
#define H_  512
#define G3_ 1536
#define EPSF 1e-15f
#define CLIPF (1.0f - 1e-5f)
#define SCOPE_AGENT __HIP_MEMORY_SCOPE_AGENT

typedef _Float16 v2h __attribute__((ext_vector_type(2)));

__device__ __forceinline__ float fdot2_(unsigned int w, unsigned int h, float c){
#if __has_builtin(__builtin_amdgcn_fdot2)
  return __builtin_amdgcn_fdot2(__builtin_bit_cast(v2h, w), __builtin_bit_cast(v2h, h), c, false);
#else
  const __half2 wh = __builtin_bit_cast(__half2, w);
  const __half2 hh = __builtin_bit_cast(__half2, h);
  return c + __low2float(wh)*__low2float(hh) + __high2float(wh)*__high2float(hh);
#endif
}

__device__ __forceinline__ float artanh_c(float x){
  x = fminf(fmaxf(x, -CLIPF), CLIPF);
  return 0.5f * logf((1.0f + x) / (1.0f - x));
}
__device__ __forceinline__ float sigmoidf_(float x){ return 1.0f/(1.0f+expf(-x)); }
__device__ __forceinline__ float hsum4(float4 v){ return (v.x+v.y)+(v.z+v.w); }

// fence-free tagged exchange (relaxed agent atomics: no cache inv/wb)
__device__ __forceinline__ void postf(unsigned long long* p, float x, unsigned tag){
  unsigned long long v = ((unsigned long long)tag << 32) |
                         (unsigned long long)__float_as_uint(x);
  __hip_atomic_store(p, v, __ATOMIC_RELAXED, SCOPE_AGENT);
}
__device__ __forceinline__ float pollf(const unsigned long long* p, unsigned tag){
  unsigned long long v = __hip_atomic_load(p, __ATOMIC_RELAXED, SCOPE_AGENT);
  while ((unsigned)(v >> 32) != tag)
    v = __hip_atomic_load(p, __ATOMIC_RELAXED, SCOPE_AGENT);
  return __uint_as_float((unsigned)v);
}

// reduce NS values across the wave; lane0 stores red[s*8 + wave] (8 waves)
template<int NS>
__device__ __forceinline__ void wave_reduce_store(float (&v)[NS], float* red, int tid){
  #pragma unroll
  for (int off = 32; off > 0; off >>= 1)
    #pragma unroll
    for (int s = 0; s < NS; s++) v[s] += __shfl_xor(v[s], off);
  if ((tid & 63) == 0)
    #pragma unroll
    for (int s = 0; s < NS; s++) red[s*8 + (tid >> 6)] = v[s];
}

// ---- transpose weight_ih [1536][512] -> WihT [512][1536]
__global__ void k_prep_ih(const float* __restrict__ Wih, float* __restrict__ WihT){
  int i = blockIdx.x * blockDim.x + threadIdx.x;
  if (i >= H_ * G3_) return;
  int k = i / G3_, n = i % G3_;
  WihT[i] = Wih[n * H_ + k];
}

__device__ __forceinline__ uint4 pack8h(const float* s){
  __half2 p0 = __halves2half2(__float2half_rn(s[0]), __float2half_rn(s[1]));
  __half2 p1 = __halves2half2(__float2half_rn(s[2]), __float2half_rn(s[3]));
  __half2 p2 = __halves2half2(__float2half_rn(s[4]), __float2half_rn(s[5]));
  __half2 p3 = __halves2half2(__float2half_rn(s[6]), __float2half_rn(s[7]));
  uint4 r;
  r.x = __builtin_bit_cast(unsigned int, p0);
  r.y = __builtin_bit_cast(unsigned int, p1);
  r.z = __builtin_bit_cast(unsigned int, p2);
  r.w = __builtin_bit_cast(unsigned int, p3);
  return r;
}

// ---- weight_hh -> register-resident layouts (f16, 8-k-wide uint4)
// WzrR[w][i<32][tid<512]: thread tid=(ks<<8)|c owns col j=128w+(c&127)
//   (c<128: z row=1024+j, else r row=j), k0 = ks*256 + i*8
// WhcR[w][q<4][i<16][c<128]: cand col j=128w+c (row 512+j), k0 = q*128 + i*8
__global__ void k_prep_hhR(const float* __restrict__ Whh, uint4* __restrict__ WzrR,
                           uint4* __restrict__ WhcR){
  int i = blockIdx.x * blockDim.x + threadIdx.x;   // 98304 total
  if (i < 65536){
    int w = i >> 14, rem = i & 16383;
    int ii = rem >> 9, tid = rem & 511;
    int c = tid & 255, ks = tid >> 8;
    int j = 128*w + (c & 127);
    int row = (c < 128) ? (1024 + j) : j;
    int k0 = ks*256 + ii*8;
    WzrR[i] = pack8h(Whh + row*H_ + k0);
  } else {
    int e = i - 65536;                              // 32768
    int w = e >> 13, rem = e & 8191;
    int q = rem >> 11, rem2 = rem & 2047;
    int ii = rem2 >> 7, c = rem2 & 127;
    int row = 512 + 128*w + c;
    int k0 = q*128 + ii*8;
    WhcR[e] = pack8h(Whh + row*H_ + k0);
  }
}

// ---- tiled f32 GEMM: C[16384][1536] = A[16384][512] * Bt[512][1536]
__global__ __launch_bounds__(256) void k_gemm(const float* __restrict__ A,
                                              const float* __restrict__ Bt,
                                              float* __restrict__ C){
  const int N = G3_, K = H_;
  const int mbase = blockIdx.x * 64, nbase = blockIdx.y * 64;
  __shared__ float As[32][65];
  __shared__ float Bs[32][65];
  const int tid = threadIdx.x;
  const int tm = tid >> 4, tn = tid & 15;
  float acc[4][4] = {};
  for (int k0 = 0; k0 < K; k0 += 32){
    #pragma unroll
    for (int i = 0; i < 8; i++){
      int e = tid + 256*i;
      int m = e >> 5, k = e & 31;
      As[k][m] = A[(size_t)(mbase + m) * K + k0 + k];
      int kk = e >> 6, n = e & 63;
      Bs[kk][n] = Bt[(size_t)(k0 + kk) * N + nbase + n];
    }
    __syncthreads();
    #pragma unroll
    for (int kk = 0; kk < 32; kk++){
      float av[4], bv[4];
      #pragma unroll
      for (int i = 0; i < 4; i++) av[i] = As[kk][tm*4+i];
      #pragma unroll
      for (int j = 0; j < 4; j++) bv[j] = Bs[kk][tn*4+j];
      #pragma unroll
      for (int i = 0; i < 4; i++)
        #pragma unroll
        for (int j = 0; j < 4; j++)
          acc[i][j] = fmaf(av[i], bv[j], acc[i][j]);
    }
    __syncthreads();
  }
  #pragma unroll
  for (int i = 0; i < 4; i++)
    #pragma unroll
    for (int j = 0; j < 4; j++)
      C[(size_t)(mbase + tm*4 + i) * N + nbase + tn*4 + j] = acc[i][j];
}

// ---- mobius_matvec tail on Ux rows
__global__ void k_nonlin(const float* __restrict__ X, float* __restrict__ D){
  const int row = blockIdx.x;
  const int lane = threadIdx.x;
  const float* x = X + (size_t)row * H_;
  float s = 0.0f;
  for (int k = lane; k < H_; k += 64){ float v = x[k]; s = fmaf(v, v, s); }
  #pragma unroll
  for (int off = 32; off > 0; off >>= 1) s += __shfl_xor(s, off);
  const float xn = fmaxf(sqrtf(s), EPSF);
  const float art = artanh_c(xn);
  float* drow = D + (size_t)row * G3_;
  for (int g = 0; g < 3; g++){
    float* mx = drow + g * H_;
    float s2 = 0.0f;
    for (int k = lane; k < H_; k += 64){ float v = mx[k]; s2 = fmaf(v, v, s2); }
    #pragma unroll
    for (int off = 32; off > 0; off >>= 1) s2 += __shfl_xor(s2, off);
    const float raw = sqrtf(s2);
    const float mn = fmaxf(raw, EPSF);
    const float scale = (raw <= EPSF) ? 0.0f : (tanhf(mn / xn * art) / mn);
    for (int k = lane; k < H_; k += 64) mx[k] *= scale;
  }
}

// ---- scan: 4 WGs/row (256 WGs x 512 thr), weights in VGPRs, fence-free sync
__global__ __launch_bounds__(512, 2) void k_scan(
    const float* __restrict__ D,        // Ux' [T*B][1536]: r|c|z col blocks
    const uint4* __restrict__ WzrR,     // [4][32][512]
    const uint4* __restrict__ WhcR,     // [4][4][16][128]
    const float* __restrict__ bias,     // [3][512] = b_r, b_c, b_z
    const float* __restrict__ h0,
    float* __restrict__ outbuf,         // [T][64][512]
    float* __restrict__ hlast,
    unsigned long long* __restrict__ hS,    // [64][512]
    unsigned long long* __restrict__ wvS,   // [64][512]
    unsigned long long* __restrict__ S1s,   // [64][4][16]
    unsigned long long* __restrict__ S3s,   // [64][4][16]
    unsigned long long* __restrict__ S4s)   // [64][4][16]
{
  const int blk = blockIdx.x;
  const int b = blk & 63, w = blk >> 6;
  const int tid = threadIdx.x;
  const int lane = tid & 63, wave = tid >> 6;
  __shared__ __align__(16) __half hh[H_];
  __shared__ __align__(16) float hf[H_];
  __shared__ __align__(16) __half wvh[H_];
  __shared__ __align__(16) float ph[512];
  __shared__ __align__(16) float red[96];
  __shared__ __align__(16) float redW[8];
  __shared__ __align__(16) float xr[16];

  unsigned long long* hRow  = hS  + b*512;
  unsigned long long* wvRow = wvS + b*512;
  unsigned long long* s1Row = S1s + b*64;
  unsigned long long* s3Row = S3s + b*64;
  unsigned long long* s4Row = S4s + b*64;

  // ---- preload weight slices into registers
  const int ks = tid >> 8;                      // phase A k-half
  const int c2 = tid & 127, q = tid >> 7;       // phase B: col + k-quarter
  const uint4* wAb = WzrR + (size_t)w*32*512 + tid;
  const uint4* wBb = WhcR + ((size_t)(w*4 + q)*16)*128 + c2;
  uint4 wA[32];
  #pragma unroll
  for (int i = 0; i < 32; i++) wA[i] = wAb[i*512];
  uint4 wB[16];
  #pragma unroll
  for (int i = 0; i < 16; i++) wB[i] = wBb[i*128];

  // initial h
  {
    const float hv0 = h0[b*H_ + tid];
    hf[tid] = hv0;
    hh[tid] = __float2half_rn(hv0);
  }
  // bias values + (local) bias norms
  const int jg = 128*w + (tid & 127);           // gate/cand col for tid<256 / tid<128
  const bool isZ = (tid < 128);
  const bool isGate = (tid < 256);
  const float bval = isGate ? (isZ ? bias[1024 + jg] : bias[jg]) : 0.f;
  const float bcj  = isZ ? bias[512 + jg] : 0.f;
  float B2own, BC2;
  {
    const float vz = bias[1024 + tid], vr = bias[tid], vc = bias[512 + tid];
    float vb[3] = { vz*vz, vr*vr, vc*vc };
    wave_reduce_store<3>(vb, red, tid);
    __syncthreads();
    const float4* p = (const float4*)red;
    const float B2z = hsum4(p[0]) + hsum4(p[1]);
    const float B2r = hsum4(p[2]) + hsum4(p[3]);
    BC2 = hsum4(p[4]) + hsum4(p[5]);
    B2own = isZ ? B2z : B2r;
    __syncthreads();
  }

  const uint4* hh4 = (const uint4*)hh;
  const uint4* wv4 = (const uint4*)wvh;
  const float* Dbase = D + (size_t)b * G3_;

  float zreg = 0.f;
  for (int t = 0; t < T_; t++){
    const unsigned tag = (unsigned)(t + 1);
    const float* U = Dbase + (size_t)t * (B_ * G3_);
    // Ux loads issue early
    const float yg = isGate ? U[(isZ ? 1024 : 0) + jg] : 0.f;
    const float yc = isZ ? U[512 + jg] : 0.f;

    // ---- h gather (posted with tag t by step t-1)
    if (t > 0){
      const float hv = pollf(hRow + tid, (unsigned)t);
      hf[tid] = hv;
      hh[tid] = __float2half_rn(hv);
    }
    __syncthreads();                                   // bar1
    const float hv = hf[tid];

    // ---- phase A: register x LDS-broadcast dot (col tid&255, k-half ks)
    float ap = 0.f;
    #pragma unroll
    for (int i = 0; i < 32; i++){
      const uint4 wr = wA[i];
      const uint4 hp = hh4[ks*32 + i];
      ap = fdot2_(wr.x, hp.x, ap);
      ap = fdot2_(wr.y, hp.y, ap);
      ap = fdot2_(wr.z, hp.z, ap);
      ap = fdot2_(wr.w, hp.w, ap);
    }
    ph[tid] = ap;
    __syncthreads();                                   // bar2
    const float a = isGate ? (ph[tid] + ph[tid + 256]) : 0.f;

    // ---- S1: local 11-slot reduce (slot0=h2 local-only; 10 gate dots exchanged)
    {
      float v[11];
      v[0] = hv*hv;
      #pragma unroll
      for (int s = 1; s < 11; s++) v[s] = 0.f;
      if (isGate){
        const int o = isZ ? 1 : 6;
        v[o] = a*a; v[o+1] = a*yg; v[o+2] = yg*yg; v[o+3] = a*bval; v[o+4] = yg*bval;
      }
      wave_reduce_store<11>(v, red, tid);
    }
    __syncthreads();                                   // bar3
    float H2;
    { const float4* p = (const float4*)red; H2 = hsum4(p[0]) + hsum4(p[1]); }
    if (wave == 0 && lane < 10){
      float s = 0.f;
      const float* r = red + (1 + lane)*8;
      #pragma unroll
      for (int i = 0; i < 8; i++) s += r[i];
      postf(s1Row + w*16 + lane, s, tag);
    }
    if (wave == 0){
      const int wgi = lane >> 4, s = lane & 15;
      float v = (s < 10) ? pollf(s1Row + wgi*16 + s, tag) : 0.f;
      v += __shfl_xor(v, 16);
      v += __shfl_xor(v, 32);
      if (lane < 16) xr[lane] = v;
    }
    __syncthreads();                                   // bar4

    // ---- gate math (threads 0..255)
    const float xn = fmaxf(sqrtf(H2), EPSF);
    const float art_h = artanh_c(xn);
    if (isGate){
      const int o = isZ ? 0 : 5;
      const float A2 = xr[o], AY = xr[o+1], Yy2 = xr[o+2], AB = xr[o+3], YB = xr[o+4];
      const float mraw = sqrtf(A2);
      const float mnc = fmaxf(mraw, EPSF);
      const float alpha = (mraw <= EPSF) ? 0.f : (tanhf(mnc/xn*art_h)/mnc);
      const float X2 = alpha*alpha*A2, XY = alpha*AY, XB = alpha*AB;
      const float cA1 = 1.f + 2.f*XY + Yy2, cB1 = 1.f - X2;
      const float den1 = fmaxf(1.f + 2.f*XY + X2*Yy2, EPSF), id1 = 1.f/den1;
      const float T2 = fmaxf((cA1*cA1*X2 + 2.f*cA1*cB1*XY + cB1*cB1*Yy2)*id1*id1, 0.f);
      const float TB = (cA1*XB + cB1*YB)*id1;
      const float cA2 = 1.f + 2.f*TB + B2own, cB2 = 1.f - T2;
      const float den2 = fmaxf(1.f + 2.f*TB + T2*B2own, EPSF), id2 = 1.f/den2;
      const float U2 = fmaxf((cA2*cA2*T2 + 2.f*cA2*cB2*TB + cB2*cB2*B2own)*id2*id2, 0.f);
      const float un = fmaxf(sqrtf(U2), EPSF);
      const float lsc = artanh_c(un)/un;
      const float t1el = (cA1*(alpha*a) + cB1*yg)*id1;
      const float uel  = (cA2*t1el + cB2*bval)*id2;
      const float g = sigmoidf_(lsc*uel);
      if (isZ) zreg = g;
      else postf(wvRow + jg, g * hf[jg], tag);
    }
    // ---- wv gather + local W2 reduce
    const float wvv = pollf(wvRow + tid, tag);
    wvh[tid] = __float2half_rn(wvv);
    {
      float v1[1] = { wvv*wvv };
      wave_reduce_store<1>(v1, redW, tid);
    }
    __syncthreads();                                   // bar5
    float W2;
    { const float4* p = (const float4*)redW; W2 = hsum4(p[0]) + hsum4(p[1]); }
    const float wraw = sqrtf(W2);
    const float wn = fmaxf(wraw, EPSF);
    const float mu = (wraw <= EPSF) ? 0.f : (tanhf(wn/xn*art_h)/wn);
    const float rhn = fmaxf(mu*wraw, EPSF);

    // ---- phase B: register x LDS-broadcast dot (col c2, k-quarter q)
    float cp = 0.f;
    #pragma unroll
    for (int i = 0; i < 16; i++){
      const uint4 wr = wB[i];
      const uint4 rp = wv4[q*16 + i];
      cp = fdot2_(wr.x, rp.x, cp);
      cp = fdot2_(wr.y, rp.y, cp);
      cp = fdot2_(wr.z, rp.z, cp);
      cp = fdot2_(wr.w, rp.w, cp);
    }
    ph[tid] = cp;
    __syncthreads();                                   // bar6
    float cel = 0.f, hj = 0.f;
    if (isZ){
      cel = mu * (ph[tid] + ph[tid+128] + ph[tid+256] + ph[tid+384]);
      hj  = hf[jg];
    }
    // ---- S3: 8 candidate dots
    {
      float v[8] = { cel*cel, cel*yc, yc*yc, cel*bcj, yc*bcj, hj*cel, hj*yc, hj*bcj };
      wave_reduce_store<8>(v, red, tid);
    }
    __syncthreads();                                   // bar7
    if (wave == 0 && lane < 8){
      float s = 0.f;
      const float* r = red + lane*8;
      #pragma unroll
      for (int i = 0; i < 8; i++) s += r[i];
      postf(s3Row + w*16 + lane, s, tag);
    }
    if (wave == 0){
      const int wgi = lane >> 4, s = lane & 15;
      float v = (s < 8) ? pollf(s3Row + wgi*16 + s, tag) : 0.f;
      v += __shfl_xor(v, 16);
      v += __shfl_xor(v, 32);
      if (lane < 16) xr[lane] = v;
    }
    __syncthreads();                                   // bar8
    const float C2 = xr[0], CY = xr[1], Y2c = xr[2], CB = xr[3],
                YBc = xr[4], HC = xr[5], HYd = xr[6], HBd = xr[7];
    const float craw = sqrtf(C2);
    const float cmn2 = fmaxf(craw, EPSF);
    const float alc = (craw <= EPSF) ? 0.f : (tanhf(cmn2/rhn*artanh_c(rhn))/cmn2);
    const float X2c = alc*alc*C2, XYc = alc*CY, XBc = alc*CB, HXc = alc*HC;
    const float cA1c = 1.f + 2.f*XYc + Y2c, cB1c = 1.f - X2c;
    const float den1c = fmaxf(1.f + 2.f*XYc + X2c*Y2c, EPSF), id1c = 1.f/den1c;
    const float T2c = fmaxf((cA1c*cA1c*X2c + 2.f*cA1c*cB1c*XYc + cB1c*cB1c*Y2c)*id1c*id1c, 0.f);
    const float TBc = (cA1c*XBc + cB1c*YBc)*id1c;
    const float HT1 = (cA1c*HXc + cB1c*HYd)*id1c;
    const float cA2c = 1.f + 2.f*TBc + BC2, cB2c = 1.f - T2c;
    const float den2c = fmaxf(1.f + 2.f*TBc + T2c*BC2, EPSF), id2c = 1.f/den2c;
    const float HTL2 = fmaxf((cA2c*cA2c*T2c + 2.f*cA2c*cB2c*TBc + cB2c*cB2c*BC2)*id2c*id2c, 0.f);
    const float HHTL = (cA2c*HT1 + cB2c*HBd)*id2c;
    const float cAd = 1.f - 2.f*HHTL + HTL2, cBd = 1.f - H2;
    const float dend = fmaxf(1.f - 2.f*HHTL + H2*HTL2, EPSF), idd = 1.f/dend;
    float del = 0.f, w2el = 0.f;
    if (isZ){
      const float t1cel = (cA1c*(alc*cel) + cB1c*yc)*id1c;
      const float htlel = (cA2c*t1cel + cB2c*bcj)*id2c;
      del = (cAd*(-hj) + cBd*htlel)*idd;
      w2el = zreg*del;
    }
    // ---- S4: {d2, |z.*d|2, h.(z.*d)}
    {
      float v[3] = { del*del, w2el*w2el, hj*w2el };
      wave_reduce_store<3>(v, red, tid);
    }
    __syncthreads();                                   // bar9
    if (wave == 0 && lane < 3){
      float s = 0.f;
      const float* r = red + lane*8;
      #pragma unroll
      for (int i = 0; i < 8; i++) s += r[i];
      postf(s4Row + w*16 + lane, s, tag);
    }
    if (wave == 0){
      const int wgi = lane >> 4, s = lane & 15;
      float v = (s < 3) ? pollf(s4Row + wgi*16 + s, tag) : 0.f;
      v += __shfl_xor(v, 16);
      v += __shfl_xor(v, 32);
      if (lane < 16) xr[lane] = v;
    }
    __syncthreads();                                   // bar10
    const float D2v = xr[0], W22 = xr[1], HW = xr[2];
    const float dnv = fmaxf(sqrtf(D2v), EPSF);
    const float w2raw = sqrtf(W22);
    const float w2n = fmaxf(w2raw, EPSF);
    const float nu = (w2raw <= EPSF) ? 0.f : (tanhf(w2n/dnv*artanh_c(dnv))/w2n);
    const float Y2f = nu*nu*W22, XYf = nu*HW;
    const float cAf = 1.f + 2.f*XYf + Y2f, cBf = 1.f - H2;
    const float denf = fmaxf(1.f + 2.f*XYf + H2*Y2f, EPSF), idf = 1.f/denf;
    if (isZ){
      const float hnew = (cAf*hj + cBf*(nu*w2el))*idf;
      outbuf[(size_t)(t*B_ + b)*H_ + jg] = hnew;
      postf(hRow + jg, hnew, tag);         // tag t+1, polled by step t+1  (R6 bug: was tag+1)
      if (t == T_-1) hlast[b*H_ + jg] = hnew;
    }
  }
}

extern "C" void kernel_launch(void* const* d_in, const int* in_sizes, int n_in,
                              void* d_out, int out_size, void* d_ws, size_t ws_size,
                              hipStream_t stream){
  (void)in_sizes; (void)n_in; (void)out_size; (void)ws_size;
  const float* input = (const float*)d_in[0];
  const float* h0    = (const float*)d_in[1];
  const float* wih1  = (const float*)d_in[2];
  const float* wih2  = (const float*)d_in[3];
  const float* whh1  = (const float*)d_in[4];
  const float* whh2  = (const float*)d_in[5];
  const float* bias1 = (const float*)d_in[6];
  const float* bias2 = (const float*)d_in[7];
  float* out = (float*)d_out;

  // ws (floats): WihT 786432 | Dbuf 25165824 | WzrR 262144 | WhcR 131072
  //              per-layer comm x2: hS 65536 | wvS 65536 | S1 8192 | S3 8192 | S4 8192
  float* A_    = (float*)d_ws;
  float* Dbuf  = A_ + 786432;
  uint4* WzrR  = (uint4*)(Dbuf + 25165824);
  uint4* WhcR  = WzrR + 65536;
  float* comm0 = (float*)(WhcR + 32768);
  unsigned long long* hS1  = (unsigned long long*)comm0;
  unsigned long long* wvS1 = hS1  + 32768;
  unsigned long long* S1a  = wvS1 + 32768;
  unsigned long long* S3a  = S1a  + 4096;
  unsigned long long* S4a  = S3a  + 4096;
  unsigned long long* hS2  = S4a  + 4096;
  unsigned long long* wvS2 = hS2  + 32768;
  unsigned long long* S1b  = wvS2 + 32768;
  unsigned long long* S3b  = S1b  + 4096;
  unsigned long long* S4b  = S3b  + 4096;

  float* out1 = out;                          // staged; consumed before scan-2 overwrites
  float* ht   = out + (size_t)T_ * B_ * H_;

  // layer 1
  k_prep_ih<<<3072, 256, 0, stream>>>(wih1, A_);
  k_gemm<<<dim3(256, 24), 256, 0, stream>>>(input, A_, Dbuf);
  k_nonlin<<<T_*B_, 64, 0, stream>>>(input, Dbuf);
  k_prep_hhR<<<384, 256, 0, stream>>>(whh1, WzrR, WhcR);
  k_scan<<<256, 512, 0, stream>>>(Dbuf, WzrR, WhcR, bias1, h0, out1, ht,
                                  hS1, wvS1, S1a, S3a, S4a);

  // layer 2
  k_prep_ih<<<3072, 256, 0, stream>>>(wih2, A_);
  k_gemm<<<dim3(256, 24), 256, 0, stream>>>(out1, A_, Dbuf);
  k_nonlin<<<T_*B_, 64, 0, stream>>>(out1, Dbuf);
  k_prep_hhR<<<384, 256, 0, stream>>>(whh2, WzrR, WhcR);
  k_scan<<<256, 512, 0, stream>>>(Dbuf, WzrR, WhcR, bias2, h0 + B_*H_, out, ht + B_*H_,
                                  hS2, wvS2, S1b, S3b, S4b);
}